// Round 18
// baseline (42.498 us; speedup 1.0000x reference)
//
#include <hip/hip_runtime.h>
#include <stdint.h>

typedef __fp16    half2v __attribute__((ext_vector_type(2)));
typedef _Float16  f16x8  __attribute__((ext_vector_type(8)));
typedef float     f32x4  __attribute__((ext_vector_type(4)));
typedef uint32_t  u32x4  __attribute__((ext_vector_type(4)));

#define KSZ    5
#define NBATCH 16
#define NC     3
#define NH     256
#define NW     256
#define TW     16
#define TH     16
#define TROWS  20
#define TWRD   12               // u32 words per tile row (24 f16 cols)
#define CPLANE (TROWS * TWRD)   // 240
#define COPYW  (NC * CPLANE)    // 720
#define PTS    20               // pbuf per-pixel stride in words (16B-aligned)
#define NUNIT  (COPYW / 2)      // 360 word-pair staging units
#define TB     4                // tiles (batches) per persistent block

__device__ __forceinline__ uint32_t pack_f16x2(float lo, float hi) {
    half2v h = __builtin_amdgcn_cvt_pkrtz(lo, hi);
    return __builtin_bit_cast(uint32_t, h);
}

__device__ __forceinline__ float fdot2(uint32_t w, uint32_t v, float acc) {
#if __has_builtin(__builtin_amdgcn_fdot2)
    return __builtin_amdgcn_fdot2(__builtin_bit_cast(half2v, w),
                                  __builtin_bit_cast(half2v, v), acc, false);
#else
    half2v a = __builtin_bit_cast(half2v, w);
    half2v b = __builtin_bit_cast(half2v, v);
    return acc + (float)a.x * (float)b.x + (float)a.y * (float)b.y;
#endif
}

// SHARED slot->pair map (r7-VERIFIED): k-slot (s, dword d) holds tap-pair P,
// halves = taps (i, 2q), (i, 2q+1), P = i*3+q.
__device__ __forceinline__ int pair_of(int s, int d) {
    return (d < 2) ? (2 * s + d) : (8 + 2 * s + (d - 2));
}

// r7-VERIFIED prep: virtual filters vf = i*6+jj (jj<5 -> f=i*5+jj, else pad).
__global__ void prep_AB(const float* __restrict__ cw, const float* __restrict__ cb,
                        uint32_t* __restrict__ Atab, float* __restrict__ cbv)
{
    int idx = threadIdx.x + blockIdx.x * 256;
    if (idx < 1536) {
        int d  = idx & 3;
        int fl = (idx >> 2) & 15;
        int s  = (idx >> 6) & 3;
        int t3 = idx >> 8;            // 0..5
        int c  = t3 % 3, mt = t3 / 3;
        int vf = mt * 16 + fl;
        int P  = pair_of(s, d);
        float lo = 0.0f, hi = 0.0f;
        if (vf < 30 && (vf % 6) != 5 && P < 15) {
            int f = (vf / 6) * 5 + (vf % 6);
            int i = P / 3, q = P - 3 * i;
            const float* base = cw + f * 75 + c * 25 + i * 5;
            lo = base[2 * q];
            if (q < 2) hi = base[2 * q + 1];
        }
        Atab[idx] = pack_f16x2(lo, hi);
    } else if (idx < 1568) {
        int vf = idx - 1536;
        float v = 0.0f;
        if (vf < 30 && (vf % 6) != 5) v = cb[(vf / 6) * 5 + (vf % 6)];
        cbv[vf] = v;
    }
}

__global__ __launch_bounds__(256, 4)
void highorder18(const float* __restrict__ x,
                 const uint32_t* __restrict__ Atab,
                 const float* __restrict__ cbv,
                 float* __restrict__ out)
{
    __shared__ uint32_t lds_t[2][2 * COPYW];     // 11520 B double-buffered tile
    __shared__ uint32_t pbuf[TH * 16 * PTS];     // 20480 B [py][px][t(20)]

    const int tid = threadIdx.x;
    const int l   = tid & 63;
    const int w   = tid >> 6;
    const int fl  = l & 15;     // A row (vf) / B col (pixel col)
    const int s   = l >> 4;     // k-slice / D row group

    const int bx  = blockIdx.x & 15;
    const int by  = (blockIdx.x >> 4) & 15;
    const int bb  = blockIdx.x >> 8;          // 0..3
    const int b0  = bb * TB;
    const int bw0 = bx * TW;
    const int bh0 = by * TH;
    const size_t bstride = (size_t)NC * NH * NW;

    // A-fragments (weights) + bias (r7-verified) — now amortized over 4 tiles
    u32x4 afr[6];
    const u32x4* At4 = (const u32x4*)Atab;
    #pragma unroll
    for (int t3 = 0; t3 < 6; ++t3)
        afr[t3] = At4[(t3 * 4 + s) * 16 + fl];
    const f32x4* cbv4 = (const f32x4*)cbv;
    const f32x4 cbA = cbv4[s];       // rows vf = 4s+r
    const f32x4 cbB = cbv4[4 + s];   // rows vf = 16+4s+r

    // Staging unit descriptors (r17-verified addressing, hoisted per-block)
    int  uoff[2], ug0[2], uidx[2];
    bool uval[2], urok[2], ufast[2];
    #pragma unroll
    for (int e = 0; e < 2; ++e) {
        int u   = tid + e * 256;
        uval[e] = (u < NUNIT);
        int uu  = uval[e] ? u : 0;
        int c   = uu / 120;            // CPLANE/2
        int rem = uu - c * 120;
        int r   = rem / 6;
        int j   = rem - r * 6;
        int gh  = bh0 + r - 2;
        int g0  = bw0 + 4 * j - 2;
        bool rowok = (unsigned)gh < NH;
        urok[e]  = rowok;
        ufast[e] = rowok && g0 >= 0 && g0 + 4 < NW;
        uoff[e]  = c * NH * NW + (rowok ? gh : 0) * NW;
        ug0[e]   = g0;
        uidx[e]  = 2 * uu;
    }

    auto ldu = [&](const float* xb, int e, float v[5]) {
        const float* row = xb + uoff[e];
        const int g0 = ug0[e];
        if (ufast[e]) {
            f32x4 t = *reinterpret_cast<const f32x4*>(row + g0);
            v[0] = t[0]; v[1] = t[1]; v[2] = t[2]; v[3] = t[3];
            v[4] = row[g0 + 4];
        } else {
            bool rk = urok[e];
            v[0] = (rk && (unsigned)(g0)     < NW) ? row[g0]     : 0.0f;
            v[1] = (rk && (unsigned)(g0 + 1) < NW) ? row[g0 + 1] : 0.0f;
            v[2] = (rk && (unsigned)(g0 + 2) < NW) ? row[g0 + 2] : 0.0f;
            v[3] = (rk && (unsigned)(g0 + 3) < NW) ? row[g0 + 3] : 0.0f;
            v[4] = (rk && (unsigned)(g0 + 4) < NW) ? row[g0 + 4] : 0.0f;
        }
    };
    auto wru = [&](uint32_t* buf, int e, const float v[5]) {
        uint2 wa; wa.x = pack_f16x2(v[0], v[1]); wa.y = pack_f16x2(v[2], v[3]);
        uint2 wb; wb.x = pack_f16x2(v[1], v[2]); wb.y = pack_f16x2(v[3], v[4]);
        *reinterpret_cast<uint2*>(&buf[uidx[e]])         = wa;
        *reinterpret_cast<uint2*>(&buf[COPYW + uidx[e]]) = wb;
    };

    // Stage tile 0 directly (r17 values, buffer 0)
    {
        const float* xb0 = x + (size_t)b0 * bstride;
        #pragma unroll
        for (int e = 0; e < 2; ++e)
            if (uval[e]) { float v[5]; ldu(xb0, e, v); wru(lds_t[0], e, v); }
    }
    __syncthreads();

    // per-lane word offsets (r7-verified)
    int woff[4];
    #pragma unroll
    for (int d = 0; d < 4; ++d) {
        int P = pair_of(s, d);
        int i = P / 3, q = P - 3 * i;
        woff[d] = (P == 15) ? 0 : (i * TWRD + q);
    }
    const int abase = ((fl & 1) ? COPYW : 0) + (fl >> 1);
    const int px  = tid & 15;
    const int py2 = tid >> 4;
    const int rb  = (py2 * 16 + px) * PTS;

    #pragma unroll
    for (int k = 0; k < TB; ++k) {
        const int cur = k & 1;
        const uint32_t* tb = lds_t[cur];

        // Issue next-tile global loads EARLY (latency hides under phase 1)
        float nx0[5], nx1[5];
        if (k < TB - 1) {
            const float* xbn = x + (size_t)(b0 + k + 1) * bstride;
            if (uval[0]) ldu(xbn, 0, nx0);
            if (uval[1]) ldu(xbn, 1, nx1);
        }

        // ---- Phase 1 (r7-verified verbatim, reading tb)
        #pragma unroll
        for (int g = 0; g < 4; ++g) {
            const int py = w * 4 + g;
            const int bg = abase + py * TWRD;

            u32x4 bv[3];
            #pragma unroll
            for (int c = 0; c < 3; ++c)
                #pragma unroll
                for (int d = 0; d < 4; ++d)
                    bv[c][d] = tb[bg + c * CPLANE + woff[d]];

            f32x4 a0 = cbA, a1 = cbB;
            #pragma unroll
            for (int c = 0; c < 3; ++c) {
                f16x8 B = __builtin_bit_cast(f16x8, bv[c]);
                a0 = __builtin_amdgcn_mfma_f32_16x16x32_f16(
                         __builtin_bit_cast(f16x8, afr[c]),     B, a0, 0, 0, 0);
                a1 = __builtin_amdgcn_mfma_f32_16x16x32_f16(
                         __builtin_bit_cast(f16x8, afr[3 + c]), B, a1, 0, 0, 0);
            }

            uint32_t wq0 = pack_f16x2(a0[0], a0[1]);
            uint32_t wq1 = pack_f16x2(a0[2], a0[3]);
            uint32_t wq2 = pack_f16x2(a1[0], a1[1]);
            uint32_t wq3 = pack_f16x2(a1[2], a1[3]);

            const int pb = (py * 16 + fl) * PTS;
            uint2 w01; w01.x = wq0; w01.y = wq1;
            uint2 w23; w23.x = wq2; w23.y = wq3;
            *reinterpret_cast<uint2*>(&pbuf[pb + 2 * s])     = w01;
            *reinterpret_cast<uint2*>(&pbuf[pb + 8 + 2 * s]) = w23;
        }

        // nb reads hoisted above the barrier (r13 win), from tb
        const uint32_t* basep = tb + ((px & 1) ? COPYW : 0) + (px >> 1);
        uint32_t nb[45];
        #pragma unroll
        for (int c = 0; c < NC; ++c)
            #pragma unroll
            for (int i = 0; i < KSZ; ++i)
                #pragma unroll
                for (int q = 0; q < 3; ++q)
                    nb[c * 15 + i * 3 + q] =
                        basep[c * CPLANE + (py2 + i) * TWRD + q];

        __syncthreads();   // pbuf ready; all reads of both tile buffers done

        // Write next tile into the alternate buffer (loads have had
        // phase1 + barrier ≈ >1000 cyc to land)
        if (k < TB - 1) {
            if (uval[0]) wru(lds_t[cur ^ 1], 0, nx0);
            if (uval[1]) wru(lds_t[cur ^ 1], 1, nx1);
        }

        // ---- Phase 2 (r13-verified verbatim), store batch b0+k
        u32x4 wp4[4];
        #pragma unroll
        for (int r = 0; r < 4; ++r)
            wp4[r] = *reinterpret_cast<const u32x4*>(&pbuf[rb + 4 * r]);

        float* ob = out + (size_t)(b0 + k) * bstride
                        + (size_t)(bh0 + py2) * NW + (bw0 + px);
        #pragma unroll
        for (int c = 0; c < NC; ++c) {
            half2v ctr = __builtin_bit_cast(half2v, nb[c * 15 + 7]);
            float sumA = (float)ctr.x;
            float sumB = 0.0f;
            #pragma unroll
            for (int t = 0; t < 8; ++t)
                sumA = fdot2(wp4[t >> 2][t & 3], nb[c * 15 + t], sumA);
            #pragma unroll
            for (int t = 8; t < 15; ++t)
                sumB = fdot2(wp4[t >> 2][t & 3], nb[c * 15 + t], sumB);
            ob[(size_t)c * NH * NW] = sumA + sumB;
        }

        if (k < TB - 1) __syncthreads();   // phase2 pbuf reads done before next
    }
}

extern "C" void kernel_launch(void* const* d_in, const int* in_sizes, int n_in,
                              void* d_out, int out_size, void* d_ws, size_t ws_size,
                              hipStream_t stream)
{
    const float* x  = (const float*)d_in[0];
    const float* cw = (const float*)d_in[1];
    const float* cb = (const float*)d_in[2];
    float* out      = (float*)d_out;
    uint32_t* Atab  = (uint32_t*)d_ws;                    // 6144 B
    float*    cbv   = (float*)((char*)d_ws + 6144);       // 128 B

    prep_AB<<<7, 256, 0, stream>>>(cw, cb, Atab, cbv);

    dim3 grid((NH / TH) * (NW / TW) * (NBATCH / TB));   // 16*16*4 = 1024 blocks
    highorder18<<<grid, 256, 0, stream>>>(x, Atab, cbv, out);
}